// Round 1
// baseline (1735.498 us; speedup 1.0000x reference)
//
#include <hip/hip_runtime.h>

#define N_NODES 16384
#define N_EDGES 8192
#define D_FEAT  64

// ws layout (floats):
//   dv : [0, 16384)
//   de : [16384, 24576)
//   Xs : [24576, 24576 + 16384*64)
//   Y  : [1073152, 1073152 + 8192*64)

__global__ __launch_bounds__(256) void dv_kernel(const float* __restrict__ H,
                                                 float* __restrict__ dv) {
    const int n = blockIdx.x;
    const float4* row = (const float4*)(H + (size_t)n * N_EDGES);
    const int t = threadIdx.x;
    float s = 0.f;
#pragma unroll
    for (int i = 0; i < 8; ++i) {
        float4 v = row[t + 256 * i];
        s += v.x + v.y + v.z + v.w;
    }
    // wave (64-lane) reduce
#pragma unroll
    for (int off = 32; off > 0; off >>= 1) s += __shfl_down(s, off, 64);
    __shared__ float wsum[4];
    if ((t & 63) == 0) wsum[t >> 6] = s;
    __syncthreads();
    if (t == 0) dv[n] = wsum[0] + wsum[1] + wsum[2] + wsum[3];
}

__global__ __launch_bounds__(256) void scalef_kernel(const float* __restrict__ F,
                                                     const float* __restrict__ dv,
                                                     float* __restrict__ Xs) {
    const int idx = blockIdx.x * 256 + threadIdx.x;  // float4 index, total N*D/4
    const int n = idx >> 4;                          // 16 float4 per row
    const float d = dv[n];
    float4 v = ((const float4*)F)[idx];
    v.x *= d; v.y *= d; v.z *= d; v.w *= d;
    ((float4*)Xs)[idx] = v;
}

// GEMM1: Y[e,d] += sum_{n in k-split} H[n,e] * Xs[n,d]; fused d_e partial sums.
// Grid: 256 = 128 e-tiles (64 edges) x 2 k-splits (8192 each).
__global__ __launch_bounds__(256) void gemm1_kernel(const float* __restrict__ H,
                                                    const float* __restrict__ Xs,
                                                    float* __restrict__ Y,
                                                    float* __restrict__ de) {
    const int et = blockIdx.x & 127;
    const int ks = blockIdx.x >> 7;
    const int e0 = et * 64;
    const int kbeg = ks * 8192;
    const int kend = kbeg + 8192;

    __shared__ float Hs[32 * 68];  // [k][e], stride 68
    __shared__ float Xt[32 * 68];  // [k][d], stride 68

    const int t = threadIdx.x;
    const int r  = t >> 4;         // staging row 0..15
    const int c4 = (t & 15) * 4;   // staging col offset
    const int eg = (t & 15) * 4;   // compute: 4 edges
    const int dg = (t >> 4) * 4;   // compute: 4 feats

    float acc[4][4] = {};
    float dea[4] = {0.f, 0.f, 0.f, 0.f};

    for (int k0 = kbeg; k0 < kend; k0 += 32) {
        __syncthreads();
#pragma unroll
        for (int i = 0; i < 2; ++i) {
            const int rr = r + 16 * i;
            float4 h = *(const float4*)(H + (size_t)(k0 + rr) * N_EDGES + e0 + c4);
            *(float4*)(Hs + rr * 68 + c4) = h;
            dea[0] += h.x; dea[1] += h.y; dea[2] += h.z; dea[3] += h.w;
            float4 x = *(const float4*)(Xs + (size_t)(k0 + rr) * D_FEAT + c4);
            *(float4*)(Xt + rr * 68 + c4) = x;
        }
        __syncthreads();
#pragma unroll 8
        for (int k = 0; k < 32; ++k) {
            float4 h = *(const float4*)(Hs + k * 68 + eg);
            float4 x = *(const float4*)(Xt + k * 68 + dg);
            acc[0][0] += h.x * x.x; acc[0][1] += h.x * x.y; acc[0][2] += h.x * x.z; acc[0][3] += h.x * x.w;
            acc[1][0] += h.y * x.x; acc[1][1] += h.y * x.y; acc[1][2] += h.y * x.z; acc[1][3] += h.y * x.w;
            acc[2][0] += h.z * x.x; acc[2][1] += h.z * x.y; acc[2][2] += h.z * x.z; acc[2][3] += h.z * x.w;
            acc[3][0] += h.w * x.x; acc[3][1] += h.w * x.y; acc[3][2] += h.w * x.z; acc[3][3] += h.w * x.w;
        }
    }

#pragma unroll
    for (int i = 0; i < 4; ++i)
#pragma unroll
        for (int j = 0; j < 4; ++j)
            atomicAdd(&Y[(size_t)(e0 + eg + i) * D_FEAT + dg + j], acc[i][j]);
#pragma unroll
    for (int j = 0; j < 4; ++j) atomicAdd(&de[e0 + c4 + j], dea[j]);
}

__global__ __launch_bounds__(256) void scaley_kernel(float* __restrict__ Y,
                                                     const float* __restrict__ de) {
    const int idx = blockIdx.x * 256 + threadIdx.x;  // float4 index, total M*D/4
    const int e = idx >> 4;
    const float d = de[e];
    float4 v = ((float4*)Y)[idx];
    v.x *= d; v.y *= d; v.z *= d; v.w *= d;
    ((float4*)Y)[idx] = v;
}

// GEMM2: out[n,d] = dv[n] * sum_e H[n,e] * Y[e,d].
// Grid: 256 blocks of 64 nodes, full-K (8192), no atomics.
__global__ __launch_bounds__(256) void gemm2_kernel(const float* __restrict__ H,
                                                    const float* __restrict__ Y,
                                                    const float* __restrict__ dv,
                                                    float* __restrict__ out) {
    const int m0 = blockIdx.x * 64;

    __shared__ float Hst[32 * 68];  // [k][m] (transposed during staging)
    __shared__ float Yt[32 * 68];   // [k][d]

    const int t = threadIdx.x;
    const int mg = (t & 15) * 4;   // compute: 4 nodes
    const int dg = (t >> 4) * 4;   // compute: 4 feats

    float acc[4][4] = {};

    for (int k0 = 0; k0 < N_EDGES; k0 += 32) {
        __syncthreads();
#pragma unroll
        for (int i = 0; i < 2; ++i) {
            const int idx = t + 256 * i;
            const int m = idx >> 3;
            const int k4 = (idx & 7) * 4;
            float4 h = *(const float4*)(H + (size_t)(m0 + m) * N_EDGES + k0 + k4);
            Hst[(k4 + 0) * 68 + m] = h.x;
            Hst[(k4 + 1) * 68 + m] = h.y;
            Hst[(k4 + 2) * 68 + m] = h.z;
            Hst[(k4 + 3) * 68 + m] = h.w;
            const int rr = idx >> 4;
            const int c4 = (idx & 15) * 4;
            float4 y = *(const float4*)(Y + (size_t)(k0 + rr) * D_FEAT + c4);
            *(float4*)(Yt + rr * 68 + c4) = y;
        }
        __syncthreads();
#pragma unroll 8
        for (int k = 0; k < 32; ++k) {
            float4 h = *(const float4*)(Hst + k * 68 + mg);
            float4 x = *(const float4*)(Yt + k * 68 + dg);
            acc[0][0] += h.x * x.x; acc[0][1] += h.x * x.y; acc[0][2] += h.x * x.z; acc[0][3] += h.x * x.w;
            acc[1][0] += h.y * x.x; acc[1][1] += h.y * x.y; acc[1][2] += h.y * x.z; acc[1][3] += h.y * x.w;
            acc[2][0] += h.z * x.x; acc[2][1] += h.z * x.y; acc[2][2] += h.z * x.z; acc[2][3] += h.z * x.w;
            acc[3][0] += h.w * x.x; acc[3][1] += h.w * x.y; acc[3][2] += h.w * x.z; acc[3][3] += h.w * x.w;
        }
    }

#pragma unroll
    for (int i = 0; i < 4; ++i) {
        const int n = m0 + mg + i;
        const float d = dv[n];
        float4 o;
        o.x = acc[i][0] * d; o.y = acc[i][1] * d; o.z = acc[i][2] * d; o.w = acc[i][3] * d;
        *(float4*)(out + (size_t)n * D_FEAT + dg) = o;
    }
}

extern "C" void kernel_launch(void* const* d_in, const int* in_sizes, int n_in,
                              void* d_out, int out_size, void* d_ws, size_t ws_size,
                              hipStream_t stream) {
    const float* H = (const float*)d_in[0];
    const float* F = (const float*)d_in[1];
    float* out = (float*)d_out;
    float* ws = (float*)d_ws;

    float* dv = ws;                         // 16384
    float* de = ws + 16384;                 // 8192
    float* Xs = ws + 24576;                 // 16384*64
    float* Y  = ws + 24576 + N_NODES * D_FEAT;  // 8192*64

    hipMemsetAsync(de, 0, N_EDGES * sizeof(float), stream);
    hipMemsetAsync(Y, 0, (size_t)N_EDGES * D_FEAT * sizeof(float), stream);

    dv_kernel<<<N_NODES, 256, 0, stream>>>(H, dv);
    scalef_kernel<<<(N_NODES * D_FEAT / 4) / 256, 256, 0, stream>>>(F, dv, Xs);
    gemm1_kernel<<<256, 256, 0, stream>>>(H, Xs, Y, de);
    scaley_kernel<<<(N_EDGES * D_FEAT / 4) / 256, 256, 0, stream>>>(Y, de);
    gemm2_kernel<<<256, 256, 0, stream>>>(H, Y, dv, out);
}

// Round 2
// 1227.671 us; speedup vs baseline: 1.4137x; 1.4137x over previous
//
#include <hip/hip_runtime.h>

#define N_NODES 16384
#define N_EDGES 8192
#define D_FEAT  64

// ws layout (floats):
//   dv   : [0, 16384)
//   de   : [16384, 24576)
//   Xs   : [24576, 1073152)                 16384*64
//   Y    : [1073152, 1597440)               8192*64
//   Yacc : [1597440, 2646016)               16384*64  (gemm2 partial accumulator)

// Fused: dv[n] = row-sum of H; Xs[n,:] = dv[n] * F[n,:].
// One wave per row, no barriers. Grid 4096 x 256 (4 rows/block).
__global__ __launch_bounds__(256, 4) void dvscale_kernel(const float* __restrict__ H,
                                                         const float* __restrict__ F,
                                                         float* __restrict__ dv,
                                                         float* __restrict__ Xs) {
    const int wave = threadIdx.x >> 6;
    const int lane = threadIdx.x & 63;
    const int n = blockIdx.x * 4 + wave;
    const float4* row = (const float4*)(H + (size_t)n * N_EDGES);
    float s = 0.f;
#pragma unroll
    for (int j = 0; j < 32; ++j) {
        float4 v = row[lane + 64 * j];
        s += v.x + v.y + v.z + v.w;
    }
#pragma unroll
    for (int off = 32; off > 0; off >>= 1) s += __shfl_down(s, off, 64);
    s = __shfl(s, 0, 64);
    if (lane == 0) dv[n] = s;
    Xs[(size_t)n * D_FEAT + lane] = F[(size_t)n * D_FEAT + lane] * s;
}

// GEMM1: Y[e,d] += sum_{n in k-chunk} H[n,e] * Xs[n,d]; fused d_e partials.
// Grid: 1024 = 128 e-tiles (64 edges) x 8 k-splits (2048 rows each).
__global__ __launch_bounds__(256, 4) void gemm1_kernel(const float* __restrict__ H,
                                                       const float* __restrict__ Xs,
                                                       float* __restrict__ Y,
                                                       float* __restrict__ de) {
    const int et = blockIdx.x & 127;
    const int ks = blockIdx.x >> 7;
    const int e0 = et * 64;
    const int kbeg = ks * 2048;
    const int kend = kbeg + 2048;

    __shared__ float Hs[32 * 68];  // [k][e], stride 68
    __shared__ float Xt[32 * 68];  // [k][d], stride 68

    const int t = threadIdx.x;
    const int r  = t >> 4;         // staging row 0..15
    const int c4 = (t & 15) * 4;   // staging col offset
    const int eg = (t & 15) * 4;   // compute: 4 edges
    const int dg = (t >> 4) * 4;   // compute: 4 feats

    float acc[4][4] = {};
    float dea[4] = {0.f, 0.f, 0.f, 0.f};

    for (int k0 = kbeg; k0 < kend; k0 += 32) {
        __syncthreads();
#pragma unroll
        for (int i = 0; i < 2; ++i) {
            const int rr = r + 16 * i;
            float4 h = *(const float4*)(H + (size_t)(k0 + rr) * N_EDGES + e0 + c4);
            *(float4*)(Hs + rr * 68 + c4) = h;
            dea[0] += h.x; dea[1] += h.y; dea[2] += h.z; dea[3] += h.w;
            float4 x = *(const float4*)(Xs + (size_t)(k0 + rr) * D_FEAT + c4);
            *(float4*)(Xt + rr * 68 + c4) = x;
        }
        __syncthreads();
#pragma unroll 8
        for (int k = 0; k < 32; ++k) {
            float4 h = *(const float4*)(Hs + k * 68 + eg);
            float4 x = *(const float4*)(Xt + k * 68 + dg);
            acc[0][0] += h.x * x.x; acc[0][1] += h.x * x.y; acc[0][2] += h.x * x.z; acc[0][3] += h.x * x.w;
            acc[1][0] += h.y * x.x; acc[1][1] += h.y * x.y; acc[1][2] += h.y * x.z; acc[1][3] += h.y * x.w;
            acc[2][0] += h.z * x.x; acc[2][1] += h.z * x.y; acc[2][2] += h.z * x.z; acc[2][3] += h.z * x.w;
            acc[3][0] += h.w * x.x; acc[3][1] += h.w * x.y; acc[3][2] += h.w * x.z; acc[3][3] += h.w * x.w;
        }
    }

#pragma unroll
    for (int i = 0; i < 4; ++i)
#pragma unroll
        for (int j = 0; j < 4; ++j)
            atomicAdd(&Y[(size_t)(e0 + eg + i) * D_FEAT + dg + j], acc[i][j]);
#pragma unroll
    for (int j = 0; j < 4; ++j) atomicAdd(&de[e0 + c4 + j], dea[j]);
}

__global__ __launch_bounds__(256) void scaley_kernel(float* __restrict__ Y,
                                                     const float* __restrict__ de) {
    const int idx = blockIdx.x * 256 + threadIdx.x;  // float4 index
    const int e = idx >> 4;
    const float d = de[e];
    float4 v = ((float4*)Y)[idx];
    v.x *= d; v.y *= d; v.z *= d; v.w *= d;
    ((float4*)Y)[idx] = v;
}

// GEMM2: Yacc[n,d] += sum_{e in k-chunk} H[n,e] * Y[e,d].
// Grid: 1024 = 256 m-tiles (64 nodes) x 4 k-splits (2048 edges each).
__global__ __launch_bounds__(256, 4) void gemm2_kernel(const float* __restrict__ H,
                                                       const float* __restrict__ Y,
                                                       float* __restrict__ Yacc) {
    const int mt = blockIdx.x & 255;
    const int ks = blockIdx.x >> 8;
    const int m0 = mt * 64;
    const int kbeg = ks * 2048;
    const int kend = kbeg + 2048;

    __shared__ float Hst[32 * 68];  // [k][m] (transposed during staging)
    __shared__ float Yt[32 * 68];   // [k][d]

    const int t = threadIdx.x;
    const int mg = (t & 15) * 4;   // compute: 4 nodes
    const int dg = (t >> 4) * 4;   // compute: 4 feats

    float acc[4][4] = {};

    for (int k0 = kbeg; k0 < kend; k0 += 32) {
        __syncthreads();
#pragma unroll
        for (int i = 0; i < 2; ++i) {
            const int idx = t + 256 * i;
            const int m = idx >> 3;
            const int k4 = (idx & 7) * 4;
            float4 h = *(const float4*)(H + (size_t)(m0 + m) * N_EDGES + k0 + k4);
            Hst[(k4 + 0) * 68 + m] = h.x;
            Hst[(k4 + 1) * 68 + m] = h.y;
            Hst[(k4 + 2) * 68 + m] = h.z;
            Hst[(k4 + 3) * 68 + m] = h.w;
            const int rr = idx >> 4;
            const int c4 = (idx & 15) * 4;
            float4 y = *(const float4*)(Y + (size_t)(k0 + rr) * D_FEAT + c4);
            *(float4*)(Yt + rr * 68 + c4) = y;
        }
        __syncthreads();
#pragma unroll 8
        for (int k = 0; k < 32; ++k) {
            float4 h = *(const float4*)(Hst + k * 68 + mg);
            float4 x = *(const float4*)(Yt + k * 68 + dg);
            acc[0][0] += h.x * x.x; acc[0][1] += h.x * x.y; acc[0][2] += h.x * x.z; acc[0][3] += h.x * x.w;
            acc[1][0] += h.y * x.x; acc[1][1] += h.y * x.y; acc[1][2] += h.y * x.z; acc[1][3] += h.y * x.w;
            acc[2][0] += h.z * x.x; acc[2][1] += h.z * x.y; acc[2][2] += h.z * x.z; acc[2][3] += h.z * x.w;
            acc[3][0] += h.w * x.x; acc[3][1] += h.w * x.y; acc[3][2] += h.w * x.z; acc[3][3] += h.w * x.w;
        }
    }

#pragma unroll
    for (int i = 0; i < 4; ++i)
#pragma unroll
        for (int j = 0; j < 4; ++j)
            atomicAdd(&Yacc[(size_t)(m0 + mg + i) * D_FEAT + dg + j], acc[i][j]);
}

// out[n,d] = dv[n] * Yacc[n,d]
__global__ __launch_bounds__(256) void scaleout_kernel(const float* __restrict__ Yacc,
                                                       const float* __restrict__ dv,
                                                       float* __restrict__ out) {
    const int idx = blockIdx.x * 256 + threadIdx.x;  // float4 index
    const int n = idx >> 4;
    const float d = dv[n];
    float4 v = ((const float4*)Yacc)[idx];
    v.x *= d; v.y *= d; v.z *= d; v.w *= d;
    ((float4*)out)[idx] = v;
}

extern "C" void kernel_launch(void* const* d_in, const int* in_sizes, int n_in,
                              void* d_out, int out_size, void* d_ws, size_t ws_size,
                              hipStream_t stream) {
    const float* H = (const float*)d_in[0];
    const float* F = (const float*)d_in[1];
    float* out = (float*)d_out;
    float* ws = (float*)d_ws;

    float* dv   = ws;                                   // 16384
    float* de   = ws + 16384;                           // 8192
    float* Xs   = ws + 24576;                           // 16384*64
    float* Y    = ws + 24576 + N_NODES * D_FEAT;        // 8192*64
    float* Yacc = Y + N_EDGES * D_FEAT;                 // 16384*64

    hipMemsetAsync(de, 0, N_EDGES * sizeof(float), stream);
    hipMemsetAsync(Y, 0, (size_t)N_EDGES * D_FEAT * sizeof(float), stream);
    hipMemsetAsync(Yacc, 0, (size_t)N_NODES * D_FEAT * sizeof(float), stream);

    dvscale_kernel<<<N_NODES / 4, 256, 0, stream>>>(H, F, dv, Xs);
    gemm1_kernel<<<1024, 256, 0, stream>>>(H, Xs, Y, de);
    scaley_kernel<<<(N_EDGES * D_FEAT / 4) / 256, 256, 0, stream>>>(Y, de);
    gemm2_kernel<<<1024, 256, 0, stream>>>(H, Y, Yacc);
    scaleout_kernel<<<(N_NODES * D_FEAT / 4) / 256, 256, 0, stream>>>(Yacc, dv, out);
}

// Round 3
// 1007.987 us; speedup vs baseline: 1.7217x; 1.2179x over previous
//
#include <hip/hip_runtime.h>

#define N_NODES 16384
#define N_EDGES 8192
#define D_FEAT  64

typedef __attribute__((ext_vector_type(8))) short short8;
typedef __attribute__((ext_vector_type(4))) float floatx4;

__device__ __forceinline__ unsigned short f2bf(float f) {
    unsigned int u = __float_as_uint(f);
    return (unsigned short)((u + 0x7fffu + ((u >> 16) & 1u)) >> 16);
}

// Swizzled LDS dword index: row-stride 32 dwords (64 bf16), XOR on group-of-4
// keeps ds_read_b128 contiguity while spreading rows across banks.
__device__ __forceinline__ int sw(int row, int g) {
    return row * 32 + (g ^ (((row >> 3) & 7) * 4));
}

// Pass 1: dv[n] = row-sum of fp32 H; Hbf = bf16(H); Xs = dv[n]*F (fp32).
__global__ __launch_bounds__(256) void dvscale_kernel(const float* __restrict__ H,
                                                      const float* __restrict__ F,
                                                      float* __restrict__ dv,
                                                      unsigned short* __restrict__ Hbf,
                                                      float* __restrict__ Xs) {
    const int wave = threadIdx.x >> 6;
    const int lane = threadIdx.x & 63;
    const int n = blockIdx.x * 4 + wave;
    const float4* row = (const float4*)(H + (size_t)n * N_EDGES);
    unsigned short* hrow = Hbf + (size_t)n * N_EDGES;
    float s = 0.f;
#pragma unroll
    for (int j = 0; j < 32; ++j) {
        float4 v = row[lane + 64 * j];
        s += v.x + v.y + v.z + v.w;
        unsigned long long pk = (unsigned long long)f2bf(v.x)
                              | ((unsigned long long)f2bf(v.y) << 16)
                              | ((unsigned long long)f2bf(v.z) << 32)
                              | ((unsigned long long)f2bf(v.w) << 48);
        *(unsigned long long*)(hrow + 4 * (lane + 64 * j)) = pk;
    }
#pragma unroll
    for (int off = 32; off > 0; off >>= 1) s += __shfl_down(s, off, 64);
    s = __shfl(s, 0, 64);
    if (lane == 0) dv[n] = s;
    Xs[(size_t)n * D_FEAT + lane] = F[(size_t)n * D_FEAT + lane] * s;
}

// Transpose Xs[16384][64] fp32 -> XsT[64][16384] bf16.
__global__ __launch_bounds__(256) void xst_kernel(const float* __restrict__ Xs,
                                                  unsigned short* __restrict__ XsT) {
    __shared__ float tile[64][65];
    const int n0 = blockIdx.x * 64;
    const int t = threadIdx.x;
    const int r = t >> 4, c4 = t & 15;
#pragma unroll
    for (int li = 0; li < 4; ++li) {
        const int rr = r + 16 * li;
        float4 v = *(const float4*)(Xs + (size_t)(n0 + rr) * 64 + c4 * 4);
        tile[rr][c4 * 4 + 0] = v.x; tile[rr][c4 * 4 + 1] = v.y;
        tile[rr][c4 * 4 + 2] = v.z; tile[rr][c4 * 4 + 3] = v.w;
    }
    __syncthreads();
#pragma unroll
    for (int li = 0; li < 4; ++li) {
        const int d = r + 16 * li;
        unsigned long long pk = (unsigned long long)f2bf(tile[c4 * 4 + 0][d])
                              | ((unsigned long long)f2bf(tile[c4 * 4 + 1][d]) << 16)
                              | ((unsigned long long)f2bf(tile[c4 * 4 + 2][d]) << 32)
                              | ((unsigned long long)f2bf(tile[c4 * 4 + 3][d]) << 48);
        *(unsigned long long*)(XsT + (size_t)d * N_NODES + n0 + c4 * 4) = pk;
    }
}

// GEMM1: YaccT[d][e] += sum_n H[n][e]*Xs[n][d]  (K=nodes, split 16x), de fused.
// Grid 1024 = 64 e-tiles(128) x 16 k-splits(1024).
__global__ __launch_bounds__(256) void gemm1_kernel(const unsigned short* __restrict__ Hbf,
                                                    const unsigned short* __restrict__ XsT,
                                                    float* __restrict__ YaccT,
                                                    float* __restrict__ de) {
    __shared__ unsigned int A32[128 * 32];  // [e][k-pair] swizzled
    __shared__ unsigned int B32[64 * 32];   // [d][k-pair] swizzled
    const int t = threadIdx.x;
    const int w = t >> 6;
    const int lane = t & 63;
    const int e0 = (blockIdx.x & 63) * 128;
    const int k0base = (blockIdx.x >> 6) * 1024;

    const int seg = t & 15;   // A: e-seg of 8
    const int p = t >> 4;     // A: node-pair 0..15 (+16)
    const int bd = t >> 3;    // B: d-row 0..31 (+32)
    const int bseg = t & 7;   // B: k-seg of 8

    floatx4 acc[2][4];
#pragma unroll
    for (int i = 0; i < 2; ++i)
#pragma unroll
        for (int j = 0; j < 4; ++j) acc[i][j] = (floatx4){0.f, 0.f, 0.f, 0.f};
    float dea[8] = {0.f, 0.f, 0.f, 0.f, 0.f, 0.f, 0.f, 0.f};

    for (int it = 0; it < 16; ++it) {
        const int k0 = k0base + it * 64;
        __syncthreads();
#pragma unroll
        for (int pp = 0; pp < 2; ++pp) {
            const int pr = p + 16 * pp;
            const unsigned short* src = Hbf + (size_t)(k0 + 2 * pr) * N_EDGES + e0 + seg * 8;
            short8 r0 = *(const short8*)src;
            short8 r1 = *(const short8*)(src + N_EDGES);
#pragma unroll
            for (int j = 0; j < 8; ++j) {
                unsigned int lo = (unsigned short)r0[j];
                unsigned int hi = (unsigned short)r1[j];
                unsigned int pk = lo | (hi << 16);
                const int e = seg * 8 + j;
                A32[sw(e, pr & ~3) + (pr & 3)] = pk;
                dea[j] += __uint_as_float(pk << 16) + __uint_as_float(pk & 0xffff0000u);
            }
        }
#pragma unroll
        for (int bb = 0; bb < 2; ++bb) {
            const int d = bd + 32 * bb;
            uint4 v = *(const uint4*)(XsT + (size_t)d * N_NODES + k0 + bseg * 8);
            *(uint4*)&B32[sw(d, bseg * 4)] = v;
        }
        __syncthreads();
#pragma unroll
        for (int s = 0; s < 2; ++s) {
            const int g = s * 16 + (lane >> 4) * 4;
            short8 af[2];
#pragma unroll
            for (int i = 0; i < 2; ++i) {
                const int row = 32 * w + 16 * i + (lane & 15);
                af[i] = *(short8*)&A32[sw(row, g)];
            }
#pragma unroll
            for (int j = 0; j < 4; ++j) {
                const int row = 16 * j + (lane & 15);
                short8 bf = *(short8*)&B32[sw(row, g)];
#pragma unroll
                for (int i = 0; i < 2; ++i)
                    acc[i][j] = __builtin_amdgcn_mfma_f32_16x16x32_bf16(af[i], bf, acc[i][j], 0, 0, 0);
            }
        }
    }

#pragma unroll
    for (int i = 0; i < 2; ++i)
#pragma unroll
        for (int j = 0; j < 4; ++j)
#pragma unroll
            for (int r = 0; r < 4; ++r) {
                const int e = e0 + 32 * w + 16 * i + (lane >> 4) * 4 + r;
                const int d = 16 * j + (lane & 15);
                atomicAdd(&YaccT[(size_t)d * N_EDGES + e], acc[i][j][r]);
            }
#pragma unroll
    for (int j = 0; j < 8; ++j) atomicAdd(&de[e0 + seg * 8 + j], dea[j]);
}

// scaley: Yt[d][e] = bf16(YaccT[d][e] * de[e]).  Grid 512.
__global__ __launch_bounds__(256) void scaley_kernel(const float* __restrict__ YaccT,
                                                     const float* __restrict__ de,
                                                     unsigned short* __restrict__ Yt) {
    const int idx = blockIdx.x * 256 + threadIdx.x;  // float4 idx over 64*8192/4
    const int d = idx >> 11;
    const int e4 = idx & 2047;
    float4 y = ((const float4*)YaccT)[idx];
    float4 sc = ((const float4*)de)[e4];
    unsigned long long pk = (unsigned long long)f2bf(y.x * sc.x)
                          | ((unsigned long long)f2bf(y.y * sc.y) << 16)
                          | ((unsigned long long)f2bf(y.z * sc.z) << 32)
                          | ((unsigned long long)f2bf(y.w * sc.w) << 48);
    *(unsigned long long*)(Yt + (size_t)d * N_EDGES + e4 * 4) = pk;
}

// GEMM2: OutAcc[n][d] += sum_e Hbf[n][e]*Yt[d][e]  (K=edges, split 8x).
// Grid 1024 = 128 m-tiles(128) x 8 k-splits(1024).
__global__ __launch_bounds__(256) void gemm2_kernel(const unsigned short* __restrict__ Hbf,
                                                    const unsigned short* __restrict__ Yt,
                                                    float* __restrict__ OutAcc) {
    __shared__ unsigned int A32[128 * 32];  // [n][k-pair] swizzled
    __shared__ unsigned int B32[64 * 32];   // [d][k-pair] swizzled
    const int t = threadIdx.x;
    const int w = t >> 6;
    const int lane = t & 63;
    const int m0 = (blockIdx.x & 127) * 128;
    const int k0base = (blockIdx.x >> 7) * 1024;

    const int aseg = t & 7;   // A: k-seg of 8
    const int am = t >> 3;    // A: m-row 0..31 (+32,+64,+96)
    const int bd = t >> 3;    // B: d-row
    const int bseg = t & 7;

    floatx4 acc[2][4];
#pragma unroll
    for (int i = 0; i < 2; ++i)
#pragma unroll
        for (int j = 0; j < 4; ++j) acc[i][j] = (floatx4){0.f, 0.f, 0.f, 0.f};

    for (int it = 0; it < 16; ++it) {
        const int k0 = k0base + it * 64;
        __syncthreads();
#pragma unroll
        for (int li = 0; li < 4; ++li) {
            const int m = am + 32 * li;
            uint4 v = *(const uint4*)(Hbf + (size_t)(m0 + m) * N_EDGES + k0 + aseg * 8);
            *(uint4*)&A32[sw(m, aseg * 4)] = v;
        }
#pragma unroll
        for (int bb = 0; bb < 2; ++bb) {
            const int d = bd + 32 * bb;
            uint4 v = *(const uint4*)(Yt + (size_t)d * N_EDGES + k0 + bseg * 8);
            *(uint4*)&B32[sw(d, bseg * 4)] = v;
        }
        __syncthreads();
#pragma unroll
        for (int s = 0; s < 2; ++s) {
            const int g = s * 16 + (lane >> 4) * 4;
            short8 af[2];
#pragma unroll
            for (int i = 0; i < 2; ++i) {
                const int row = 32 * w + 16 * i + (lane & 15);
                af[i] = *(short8*)&A32[sw(row, g)];
            }
#pragma unroll
            for (int j = 0; j < 4; ++j) {
                const int row = 16 * j + (lane & 15);
                short8 bf = *(short8*)&B32[sw(row, g)];
#pragma unroll
                for (int i = 0; i < 2; ++i)
                    acc[i][j] = __builtin_amdgcn_mfma_f32_16x16x32_bf16(af[i], bf, acc[i][j], 0, 0, 0);
            }
        }
    }

#pragma unroll
    for (int i = 0; i < 2; ++i)
#pragma unroll
        for (int j = 0; j < 4; ++j)
#pragma unroll
            for (int r = 0; r < 4; ++r) {
                const int n = m0 + 32 * w + 16 * i + (lane >> 4) * 4 + r;
                const int d = 16 * j + (lane & 15);
                atomicAdd(&OutAcc[(size_t)n * D_FEAT + d], acc[i][j][r]);
            }
}

// out[n][d] = OutAcc[n][d] * dv[n].  Grid 1024.
__global__ __launch_bounds__(256) void scaleout_kernel(const float* __restrict__ OutAcc,
                                                       const float* __restrict__ dv,
                                                       float* __restrict__ out) {
    const int idx = blockIdx.x * 256 + threadIdx.x;
    const int n = idx >> 4;
    const float d = dv[n];
    float4 v = ((const float4*)OutAcc)[idx];
    v.x *= d; v.y *= d; v.z *= d; v.w *= d;
    ((float4*)out)[idx] = v;
}

extern "C" void kernel_launch(void* const* d_in, const int* in_sizes, int n_in,
                              void* d_out, int out_size, void* d_ws, size_t ws_size,
                              hipStream_t stream) {
    const float* H = (const float*)d_in[0];
    const float* F = (const float*)d_in[1];
    float* out = (float*)d_out;
    char* base = (char*)d_ws;

    float* dv = (float*)base;                                   // 64 KiB
    float* de = (float*)(base + 65536);                         // 32 KiB
    float* Xs = (float*)(base + 98304);                         // 4 MiB
    float* YaccT = (float*)(base + 98304 + 4194304);            // 2 MiB
    float* OutAcc = (float*)(base + 98304 + 4194304 + 2097152); // 4 MiB
    unsigned short* XsT = (unsigned short*)(base + 98304 + 4194304 + 2097152 + 4194304);  // 2 MiB
    unsigned short* Yt = XsT + (size_t)64 * N_NODES;            // 1 MiB
    unsigned short* Hbf = (unsigned short*)((char*)Yt + 1048576);  // 256 MiB

    hipMemsetAsync(de, 0, N_EDGES * sizeof(float), stream);
    hipMemsetAsync(YaccT, 0, (size_t)64 * N_EDGES * sizeof(float), stream);
    hipMemsetAsync(OutAcc, 0, (size_t)N_NODES * D_FEAT * sizeof(float), stream);

    dvscale_kernel<<<N_NODES / 4, 256, 0, stream>>>(H, F, dv, Hbf, Xs);
    xst_kernel<<<N_NODES / 64, 256, 0, stream>>>(Xs, XsT);
    gemm1_kernel<<<1024, 256, 0, stream>>>(Hbf, XsT, YaccT, de);
    scaley_kernel<<<512, 256, 0, stream>>>(YaccT, de, Yt);
    gemm2_kernel<<<1024, 256, 0, stream>>>(Hbf, Yt, OutAcc);
    scaleout_kernel<<<1024, 256, 0, stream>>>(OutAcc, dv, out);
}